// Round 17
// baseline (7092.036 us; speedup 1.0000x reference)
//
#include <hip/hip_runtime.h>

typedef _Float16 f16;
typedef _Float16 f16x8 __attribute__((ext_vector_type(8)));
typedef _Float16 f16x4 __attribute__((ext_vector_type(4)));
typedef float f32x4 __attribute__((ext_vector_type(4)));

#define H_    256
#define TB_   64      // batch rows per workgroup
#define NT_   512     // 8 waves; TWO independent WGs co-resident per CU (16 waves = reg cap)
#define SORB_ 64
#define SLOT_ 8192    // 32 rows * 256 cols f16 = 16 KB

#define MFMA16(a, b, c) __builtin_amdgcn_mfma_f32_16x16x32_f16((a), (b), (c), 0, 0, 0)
#define UNR _Pragma("unroll")

__device__ __forceinline__ float sigm(float v) {
  return __builtin_amdgcn_rcpf(1.0f + __builtin_amdgcn_exp2f(v * -1.442695040888963f));
}
__device__ __forceinline__ float tanh_fast(float v) {
  float a = fabsf(v);
  float e = __builtin_amdgcn_exp2f(a * -2.885390081777927f);
  float t = (1.0f - e) * __builtin_amdgcn_rcpf(1.0f + e);
  return copysignf(t, v);
}
// XOR-swizzle within a 32-row slot (f16 units, 16B granule)
__device__ __forceinline__ int lswz(int lrow, int col) {
  return lrow * H_ + (col ^ ((lrow & 7) << 3));
}

// fp32 -> f16 weight conversion: [whh0 | wih1 | whh1], each [768][256] row-major
__global__ void wcvt(const float* __restrict__ a, const float* __restrict__ b,
                     const float* __restrict__ c, f16* __restrict__ o) {
  int i = blockIdx.x * 256 + threadIdx.x;
  const int n = 768 * 256;
  if (i < n) {
    o[i]         = (f16)a[i];
    o[n + i]     = (f16)b[i];
    o[2 * n + i] = (f16)c[i];
  }
}

// 2 WGs/CU: LDS 79.4 KB/WG (x2 = 158.7 <= 160). In-place h updates via 4-VGPR
// register staging behind barriers (4 barriers/step). Reg cap 64 arch + 64 acc:
// per-col gate constants live in an LDS table, not registers.
__global__ __launch_bounds__(NT_, 4) void rnnwf(
    const int* __restrict__ x,
    const float* __restrict__ w_ih0, const float* __restrict__ b_ih0,
    const float* __restrict__ b_hh0, const float* __restrict__ b_ih1,
    const float* __restrict__ b_hh1, const float* __restrict__ w_amp,
    const float* __restrict__ b_amp, const f16* __restrict__ W16,
    float* __restrict__ out)
{
  __shared__ __align__(16) f16 hall[4 * SLOT_];  // 64 KB: h0 = slots 0-1, h1 = slots 2-3
  __shared__ float tabL[11 * 256];               // 11 KB per-col gate constants
  __shared__ float wampL[512];
  __shared__ unsigned long long bitsT[SORB_];

  const int tid  = threadIdx.x;
  const int wave = tid >> 6;                  // 0..7
  const int lane = tid & 63;
  const int l15  = lane & 15;
  const int lg   = lane >> 4;                 // 0..3
  const int lg4  = lg << 2;
  const int col  = wave * 16 + l15;           // 0..127; nt=1 adds 128
  const int rowbase = blockIdx.x * TB_;

  // ---- one-time setup ----
  for (int j = tid; j < 512; j += NT_) wampL[j] = w_amp[j];
  for (int j = tid; j < 256; j += NT_) {
    float bR = b_ih0[j] + b_hh0[j];
    float bZ = b_ih0[256 + j] + b_hh0[256 + j];
    float bN = b_ih0[512 + j];
    float r0 = w_ih0[2 * j],           r1 = w_ih0[2 * j + 1];
    float z0 = w_ih0[2 * (256 + j)],   z1 = w_ih0[2 * (256 + j) + 1];
    float n0 = w_ih0[2 * (512 + j)],   n1 = w_ih0[2 * (512 + j) + 1];
    tabL[j]          = bR + r0;  tabL[256 + j]  = r1 - r0;
    tabL[512 + j]    = bZ + z0;  tabL[768 + j]  = z1 - z0;
    tabL[1024 + j]   = bN + n0;  tabL[1280 + j] = n1 - n0;
    tabL[1536 + j]   = b_hh0[512 + j];
    tabL[1792 + j]   = b_ih1[j] + b_hh1[j];
    tabL[2048 + j]   = b_ih1[256 + j] + b_hh1[256 + j];
    tabL[2304 + j]   = b_ih1[512 + j];
    tabL[2560 + j]   = b_hh1[512 + j];
  }
  if (tid < TB_ * 4) {                 // pack bits into hall scratch (u16 per quarter-row)
    const int* xp = x + (size_t)(rowbase + (tid >> 2)) * SORB_ + (tid & 3) * 16;
    unsigned m = 0;
    #pragma unroll
    for (int i = 0; i < 16; ++i) m |= (unsigned)(xp[i] & 1) << i;
    ((unsigned short*)hall)[tid] = (unsigned short)m;
  }
  __syncthreads();
  if (tid < SORB_) {                   // bitsT[t]: bit r = x[row r][t]
    unsigned long long mk = 0ull;
    const int q = tid >> 4, sh = tid & 15;
    #pragma unroll 4
    for (int r = 0; r < TB_; ++r)
      mk |= (unsigned long long)((((const unsigned short*)hall)[r * 4 + q] >> sh) & 1) << r;
    bitsT[tid] = mk;
  }
  const unsigned long long hmk = ((const unsigned long long*)hall)[tid >> 3];  // head row mask
  __syncthreads();
  for (int i = tid; i < 4 * SLOT_; i += NT_) hall[i] = (f16)0.f;
  const float ba0 = b_amp[0], ba1 = b_amp[1];
  __syncthreads();

  float prob = 1.0f;
  const f16* p0base = W16 + col * 256;
  const f16* pibase = W16 + 768 * 256 + col * 256;
  const f16* phbase = W16 + 2 * 768 * 256 + col * 256;
  const int hrow = tid >> 3;           // head: 64 rows, 8 threads each
  const int t8   = tid & 7;

  for (int t = -1; t < SORB_; ++t) {
    unsigned lo32 = 0u, hi32 = 0u;
    if (t >= 0) {
      unsigned long long mk = bitsT[t];        // uniform address -> broadcast
      lo32 = (unsigned)mk; hi32 = (unsigned)(mk >> 32);
    }

    // ========== layer 0: MFMA reads h0 (slots 0-1); result staged in regs ==========
    f16x4 s0[8];
    UNR for (int nt = 0; nt < 2; ++nt) {
      const int c = col + nt * 128;
      const f16* pw = p0base + nt * 32768;
      f32x4 aR[4], aZ[4], aN[4];
      UNR for (int m = 0; m < 4; ++m) { aR[m] = (f32x4){0,0,0,0}; aZ[m] = aR[m]; aN[m] = aR[m]; }
      #pragma unroll 2
      for (int kt = 0; kt < 8; ++kt) {
        const int k0 = kt * 32 + lg * 8;
        f16x8 Br = *(const f16x8*)(pw + k0);
        f16x8 Bz = *(const f16x8*)(pw + 65536 + k0);
        f16x8 Bn = *(const f16x8*)(pw + 131072 + k0);
        UNR for (int m = 0; m < 4; ++m) {
          f16x8 A = *(const f16x8*)&hall[(m >> 1) * SLOT_ + lswz((m & 1) * 16 + l15, k0)];
          aR[m] = MFMA16(A, Br, aR[m]);
          aZ[m] = MFMA16(A, Bz, aZ[m]);
          aN[m] = MFMA16(A, Bn, aN[m]);
        }
      }
      if (t >= 0) {
        const float sR = tabL[c],        dRv = tabL[256 + c];
        const float sZ = tabL[512 + c],  dZv = tabL[768 + c];
        const float sN = tabL[1024 + c], dNv = tabL[1280 + c];
        const float bh0n = tabL[1536 + c];
        UNR for (int m = 0; m < 4; ++m) {
          const unsigned hsel = (m < 2) ? lo32 : hi32;
          UNR for (int e = 0; e < 4; ++e) {
            const int lrow = (m & 1) * 16 + lg4 + e;
            float fb = (float)((hsel >> ((m & 1) * 16 + lg4 + e)) & 1u);
            float r  = sigm(aR[m][e] + fmaf(fb, dRv, sR));
            float z  = sigm(aZ[m][e] + fmaf(fb, dZv, sZ));
            float n  = tanh_fast(fmaf(fb, dNv, sN) + r * (aN[m][e] + bh0n));
            float ho = (float)hall[(m >> 1) * SLOT_ + lswz(lrow, c)];
            s0[nt * 4 + m][e] = (f16)((1.0f - z) * n + z * ho);
          }
        }
      } else {  // priming step: cold path, constants from global
        const float pR = b_ih0[c] + b_hh0[c];
        const float pZ = b_ih0[256 + c] + b_hh0[256 + c];
        const float pN = b_ih0[512 + c];
        const float bh0n = b_hh0[512 + c];
        UNR for (int m = 0; m < 4; ++m) {
          UNR for (int e = 0; e < 4; ++e) {
            const int lrow = (m & 1) * 16 + lg4 + e;
            float r  = sigm(aR[m][e] + pR);
            float z  = sigm(aZ[m][e] + pZ);
            float n  = tanh_fast(pN + r * (aN[m][e] + bh0n));
            float ho = (float)hall[(m >> 1) * SLOT_ + lswz(lrow, c)];
            s0[nt * 4 + m][e] = (f16)((1.0f - z) * n + z * ho);
          }
        }
      }
    }
    __syncthreads();                   // all h0 reads done
    UNR for (int nt = 0; nt < 2; ++nt) {
      const int c = col + nt * 128;
      UNR for (int m = 0; m < 4; ++m)
        UNR for (int e = 0; e < 4; ++e)
          hall[(m >> 1) * SLOT_ + lswz((m & 1) * 16 + lg4 + e, c)] = s0[nt * 4 + m][e];
    }
    __syncthreads();                   // h0_new visible

    // ========== layer 1: reads h0' (slots 0-1) + h1 (slots 2-3); staged ==========
    f16x4 s1[8];
    UNR for (int nt = 0; nt < 2; ++nt) {
      const int c = col + nt * 128;
      const f16* pib = pibase + nt * 32768;
      const f16* phb = phbase + nt * 32768;
      f32x4 tR[4], tZ[4], tNi[4], tNh[4];
      UNR for (int m = 0; m < 4; ++m) {
        tR[m] = (f32x4){0,0,0,0}; tZ[m] = tR[m]; tNi[m] = tR[m]; tNh[m] = tR[m];
      }
      #pragma unroll 1
      for (int kt = 0; kt < 8; ++kt) {
        const int k0 = kt * 32 + lg * 8;
        {  // ih source
          f16x8 BiR = *(const f16x8*)(pib + k0);
          f16x8 BiZ = *(const f16x8*)(pib + 65536 + k0);
          f16x8 BiN = *(const f16x8*)(pib + 131072 + k0);
          UNR for (int m = 0; m < 4; ++m) {
            f16x8 A0 = *(const f16x8*)&hall[(m >> 1) * SLOT_ + lswz((m & 1) * 16 + l15, k0)];
            tR[m]  = MFMA16(A0, BiR, tR[m]);
            tZ[m]  = MFMA16(A0, BiZ, tZ[m]);
            tNi[m] = MFMA16(A0, BiN, tNi[m]);
          }
        }
        {  // hh source
          f16x8 BhR = *(const f16x8*)(phb + k0);
          f16x8 BhZ = *(const f16x8*)(phb + 65536 + k0);
          f16x8 BhN = *(const f16x8*)(phb + 131072 + k0);
          UNR for (int m = 0; m < 4; ++m) {
            f16x8 A1 = *(const f16x8*)&hall[2 * SLOT_ + (m >> 1) * SLOT_ + lswz((m & 1) * 16 + l15, k0)];
            tR[m]  = MFMA16(A1, BhR, tR[m]);
            tZ[m]  = MFMA16(A1, BhZ, tZ[m]);
            tNh[m] = MFMA16(A1, BhN, tNh[m]);
          }
        }
      }
      const float c1r  = tabL[1792 + c], c1z  = tabL[2048 + c];
      const float c1ni = tabL[2304 + c], c1nh = tabL[2560 + c];
      UNR for (int m = 0; m < 4; ++m) {
        UNR for (int e = 0; e < 4; ++e) {
          const int lrow = (m & 1) * 16 + lg4 + e;
          float r  = sigm(tR[m][e] + c1r);
          float z  = sigm(tZ[m][e] + c1z);
          float n  = tanh_fast(tNi[m][e] + c1ni + r * (tNh[m][e] + c1nh));
          float ho = (float)hall[2 * SLOT_ + (m >> 1) * SLOT_ + lswz(lrow, c)];
          s1[nt * 4 + m][e] = (f16)((1.0f - z) * n + z * ho);
        }
      }
    }
    __syncthreads();                   // all h0'/h1 reads done
    UNR for (int nt = 0; nt < 2; ++nt) {
      const int c = col + nt * 128;
      UNR for (int m = 0; m < 4; ++m)
        UNR for (int e = 0; e < 4; ++e)
          hall[2 * SLOT_ + (m >> 1) * SLOT_ + lswz((m & 1) * 16 + lg4 + e, c)] = s1[nt * 4 + m][e];
    }
    __syncthreads();                   // h1_new visible

    // ========== amplitude head (reads h1_new in slots 2-3) ==========
    if (t >= 0) {
      float d0 = 0.f, d1 = 0.f;
      #pragma unroll
      for (int j = 0; j < 4; ++j) {
        const int k0 = t8 * 32 + j * 8;
        f16x8 hv = *(const f16x8*)&hall[2 * SLOT_ + (hrow >> 5) * SLOT_ + lswz(hrow & 31, k0)];
        f32x4 w0a = *(const f32x4*)&wampL[k0];
        f32x4 w0b = *(const f32x4*)&wampL[k0 + 4];
        f32x4 w1a = *(const f32x4*)&wampL[256 + k0];
        f32x4 w1b = *(const f32x4*)&wampL[256 + k0 + 4];
        #pragma unroll
        for (int i = 0; i < 4; ++i) {
          float hfa = (float)hv[i], hfb = (float)hv[4 + i];
          d0 = fmaf(hfa, w0a[i], d0); d0 = fmaf(hfb, w0b[i], d0);
          d1 = fmaf(hfa, w1a[i], d1); d1 = fmaf(hfb, w1b[i], d1);
        }
      }
      d0 += __shfl_xor(d0, 1); d0 += __shfl_xor(d0, 2); d0 += __shfl_xor(d0, 4);
      d1 += __shfl_xor(d1, 1); d1 += __shfl_xor(d1, 2); d1 += __shfl_xor(d1, 4);
      const int bit = (unsigned)(hmk >> t) & 1u;
      float diff = (d0 + ba0) - (d1 + ba1);
      if (bit) diff = -diff;
      prob *= __builtin_amdgcn_rcpf(1.0f + __builtin_amdgcn_exp2f(diff * -1.442695040888963f));
    }
  }

  if (t8 == 0) out[rowbase + hrow] = sqrtf(prob);
}

extern "C" void kernel_launch(void* const* d_in, const int* in_sizes, int n_in,
                              void* d_out, int out_size, void* d_ws, size_t ws_size,
                              hipStream_t stream) {
  const int*   x     = (const int*)d_in[0];
  const float* w_ih0 = (const float*)d_in[1];
  const float* w_hh0 = (const float*)d_in[2];
  const float* b_ih0 = (const float*)d_in[3];
  const float* b_hh0 = (const float*)d_in[4];
  const float* w_ih1 = (const float*)d_in[5];
  const float* w_hh1 = (const float*)d_in[6];
  const float* b_ih1 = (const float*)d_in[7];
  const float* b_hh1 = (const float*)d_in[8];
  const float* w_amp = (const float*)d_in[9];
  const float* b_amp = (const float*)d_in[10];
  (void)in_sizes; (void)n_in; (void)out_size; (void)ws_size;

  f16* W16 = (f16*)d_ws;   // 3*768*256*2 = 1.18 MB of workspace
  hipLaunchKernelGGL(wcvt, dim3(768), dim3(256), 0, stream, w_hh0, w_ih1, w_hh1, W16);
  hipLaunchKernelGGL(rnnwf, dim3(32768 / TB_), dim3(NT_), 0, stream,
                     x, w_ih0, b_ih0, b_hh0, b_ih1, b_hh1, w_amp, b_amp, W16,
                     (float*)d_out);
}

// Round 18
// 5553.541 us; speedup vs baseline: 1.2770x; 1.2770x over previous
//
#include <hip/hip_runtime.h>

typedef _Float16 f16;
typedef _Float16 f16x8 __attribute__((ext_vector_type(8)));
typedef float f32x4 __attribute__((ext_vector_type(4)));

#define H_    256
#define TB_   64      // batch rows per workgroup
#define NT_   1024    // 16 waves, 4 per SIMD
#define SORB_ 64
#define SLOT_ 8192    // 32 rows * 256 cols f16 = 16 KB; a pair (64 rows) = 2 slots

#define MFMA16(a, b, c) __builtin_amdgcn_mfma_f32_16x16x32_f16((a), (b), (c), 0, 0, 0)
#define UNR _Pragma("unroll")

// fast activations: native v_exp_f32 (computes 2^x) + v_rcp_f32; rel err ~1e-7
__device__ __forceinline__ float sigm(float v) {
  return __builtin_amdgcn_rcpf(1.0f + __builtin_amdgcn_exp2f(v * -1.442695040888963f));
}
__device__ __forceinline__ float tanh_fast(float v) {
  float a = fabsf(v);
  float e = __builtin_amdgcn_exp2f(a * -2.885390081777927f);
  float t = (1.0f - e) * __builtin_amdgcn_rcpf(1.0f + e);
  return copysignf(t, v);
}
// XOR-swizzle within a 32-row slot (f16 units, 16B granule)
__device__ __forceinline__ int lswz(int lrow, int col) {
  return lrow * H_ + (col ^ ((lrow & 7) << 3));
}

// fp32 -> f16 weight conversion: [whh0 | wih1 | whh1], each [768][256] row-major
__global__ void wcvt(const float* __restrict__ a, const float* __restrict__ b,
                     const float* __restrict__ c, f16* __restrict__ o) {
  int i = blockIdx.x * 256 + threadIdx.x;
  const int n = 768 * 256;
  if (i < n) {
    o[i]         = (f16)a[i];
    o[n + i]     = (f16)b[i];
    o[2 * n + i] = (f16)c[i];
  }
}

__global__ __launch_bounds__(NT_, 4) void rnnwf(
    const int* __restrict__ x,
    const float* __restrict__ w_ih0, const float* __restrict__ b_ih0,
    const float* __restrict__ b_hh0, const float* __restrict__ b_ih1,
    const float* __restrict__ b_hh1, const float* __restrict__ w_amp,
    const float* __restrict__ b_amp, const f16* __restrict__ W16,
    float* __restrict__ out)
{
  __shared__ __align__(16) f16 hall[6 * SLOT_];  // 96 KB: 3 pairs of 64 rows
  __shared__ float wampL[512];
  __shared__ unsigned short bitsL[TB_ * 4];
  __shared__ unsigned long long bitsT[SORB_];    // bit r of bitsT[t] = x[row r][t]

  const int tid  = threadIdx.x;
  const int wave = tid >> 6;                  // 0..15
  const int lane = tid & 63;
  const int l15  = lane & 15;
  const int lg   = lane >> 4;                 // 0..3
  const int lg4  = lg << 2;
  const int col  = wave * 16 + l15;           // fixed hidden column per thread
  const int rowbase = blockIdx.x * TB_;

  // ---- one-time setup ----
  for (int j = tid; j < 512; j += NT_) wampL[j] = w_amp[j];
  if (tid < 256) {
    int row = tid >> 2, q = tid & 3;
    const int* xp = x + (size_t)(rowbase + row) * SORB_ + q * 16;
    unsigned m = 0;
    #pragma unroll
    for (int i = 0; i < 16; ++i) m |= (unsigned)(xp[i] & 1) << i;
    bitsL[row * 4 + q] = (unsigned short)m;
  }
  for (int i = tid; i < 6 * SLOT_; i += NT_) hall[i] = (f16)0.f;

  // per-thread L0 gate tables: sum0 (bit=0) and sum1 (bit=1) per gate.
  // sum1 = sum0 + delta rounded once -- bitwise-identical to the fma it replaces.
  const float baseR = b_ih0[col]       + b_hh0[col];
  const float baseZ = b_ih0[256 + col] + b_hh0[256 + col];
  const float baseN = b_ih0[512 + col];
  const float sumR0 = baseR + w_ih0[2 * col + 0];
  const float sumZ0 = baseZ + w_ih0[2 * (256 + col) + 0];
  const float sumN0 = baseN + w_ih0[2 * (512 + col) + 0];
  const float sumR1 = sumR0 + (w_ih0[2 * col + 1]         - w_ih0[2 * col + 0]);
  const float sumZ1 = sumZ0 + (w_ih0[2 * (256 + col) + 1] - w_ih0[2 * (256 + col) + 0]);
  const float sumN1 = sumN0 + (w_ih0[2 * (512 + col) + 1] - w_ih0[2 * (512 + col) + 0]);
  const float bhh0n_c = b_hh0[512 + col];
  const float b1r_c   = b_ih1[col]       + b_hh1[col];
  const float b1z_c   = b_ih1[256 + col] + b_hh1[256 + col];
  const float b1ni_c  = b_ih1[512 + col];
  const float b1nh_c  = b_hh1[512 + col];
  const float ba0 = b_amp[0], ba1 = b_amp[1];
  __syncthreads();

  // transpose bit matrix: bitsT[t] holds bit-per-row for step t (broadcast read later)
  if (tid < SORB_) {
    unsigned long long mk = 0ull;
    const int q = tid >> 4, sh = tid & 15;
    #pragma unroll 4
    for (int r = 0; r < TB_; ++r)
      mk |= (unsigned long long)((bitsL[r * 4 + q] >> sh) & 1) << r;
    bitsT[tid] = mk;
  }
  __syncthreads();

  float prob = 1.0f;
  const f16* Wih1 = W16 + 768 * 256;
  const f16* Whh1 = W16 + 2 * 768 * 256;
  const f16* p0base = W16  + col * 256;
  const f16* pibase = Wih1 + col * 256;
  const f16* phbase = Whh1 + col * 256;

  // head constants
  const int hrow = tid >> 4;            // 0..63
  const int t16  = tid & 15;
  const int hsh  = hrow & 31;
  const bool hhi = hrow >= 32;

  int pa = 0, pb = 2 * SLOT_, pc = 4 * SLOT_;   // h0_cur, h1_cur, free

  for (int t = -1; t < SORB_; ++t) {
    unsigned lo32 = 0u, hi32 = 0u;
    if (t >= 0) {
      unsigned long long mk = bitsT[t];        // uniform address -> broadcast
      lo32 = (unsigned)mk; hi32 = (unsigned)(mk >> 32);
    }

    // ================= layer 0: read pa -> write pc =================
    {
      f32x4 aR[4], aZ[4], aN[4];
      UNR for (int m = 0; m < 4; ++m) { aR[m] = (f32x4){0,0,0,0}; aZ[m] = aR[m]; aN[m] = aR[m]; }
      #pragma unroll 2
      for (int kt = 0; kt < 8; ++kt) {
        const int k0 = kt * 32 + lg * 8;
        f16x8 Br = *(const f16x8*)(p0base + k0);
        f16x8 Bz = *(const f16x8*)(p0base + 65536 + k0);
        f16x8 Bn = *(const f16x8*)(p0base + 131072 + k0);
        UNR for (int m = 0; m < 4; ++m) {
          f16x8 A = *(const f16x8*)&hall[pa + (m >> 1) * SLOT_ + lswz((m & 1) * 16 + l15, k0)];
          aR[m] = MFMA16(A, Br, aR[m]);
          aZ[m] = MFMA16(A, Bz, aZ[m]);
          aN[m] = MFMA16(A, Bn, aN[m]);
        }
      }
      if (t >= 0) {
        UNR for (int m = 0; m < 4; ++m) {
          const unsigned hsel = (m < 2) ? lo32 : hi32;
          UNR for (int e = 0; e < 4; ++e) {
            const int lrow = (m & 1) * 16 + lg4 + e;
            const bool bset = (hsel >> ((m & 1) * 16 + lg4 + e)) & 1u;
            float r  = sigm(aR[m][e] + (bset ? sumR1 : sumR0));
            float z  = sigm(aZ[m][e] + (bset ? sumZ1 : sumZ0));
            float n  = tanh_fast((bset ? sumN1 : sumN0) + r * (aN[m][e] + bhh0n_c));
            float ho = (float)hall[pa + (m >> 1) * SLOT_ + lswz(lrow, col)];
            hall[pc + (m >> 1) * SLOT_ + lswz(lrow, col)] = (f16)(n + z * (ho - n));
          }
        }
      } else {
        UNR for (int m = 0; m < 4; ++m) {
          UNR for (int e = 0; e < 4; ++e) {
            const int lrow = (m & 1) * 16 + lg4 + e;
            float r  = sigm(aR[m][e] + baseR);
            float z  = sigm(aZ[m][e] + baseZ);
            float n  = tanh_fast(baseN + r * (aN[m][e] + bhh0n_c));
            float ho = (float)hall[pa + (m >> 1) * SLOT_ + lswz(lrow, col)];
            hall[pc + (m >> 1) * SLOT_ + lswz(lrow, col)] = (f16)(n + z * (ho - n));
          }
        }
      }
    }
    __syncthreads();

    // ===== layer 1: read pc (h0') + pb (h1) -> write pa =====
    // ONE kt loop, four gate accumulator sets (64 accs -> AGPR file), B loaded
    // once per kt, A0/A1 once per kt. unroll 2 for cross-kt load/MFMA overlap
    // (L2-latency hiding); element-wise epilogue keeps arch live-set < 64.
    {
      f32x4 tR[4], tZ[4], tNi[4], tNh[4];
      UNR for (int m = 0; m < 4; ++m) {
        tR[m] = (f32x4){0,0,0,0}; tZ[m] = tR[m]; tNi[m] = tR[m]; tNh[m] = tR[m];
      }
      #pragma unroll 2
      for (int kt = 0; kt < 8; ++kt) {
        const int k0 = kt * 32 + lg * 8;
        {  // ih source: 3 B streams live, A0 loaded per-m
          f16x8 BiR = *(const f16x8*)(pibase + k0);
          f16x8 BiZ = *(const f16x8*)(pibase + 65536 + k0);
          f16x8 BiN = *(const f16x8*)(pibase + 131072 + k0);
          UNR for (int m = 0; m < 4; ++m) {
            f16x8 A0 = *(const f16x8*)&hall[pc + (m >> 1) * SLOT_ + lswz((m & 1) * 16 + l15, k0)];
            tR[m]  = MFMA16(A0, BiR, tR[m]);
            tZ[m]  = MFMA16(A0, BiZ, tZ[m]);
            tNi[m] = MFMA16(A0, BiN, tNi[m]);
          }
        }
        {  // hh source
          f16x8 BhR = *(const f16x8*)(phbase + k0);
          f16x8 BhZ = *(const f16x8*)(phbase + 65536 + k0);
          f16x8 BhN = *(const f16x8*)(phbase + 131072 + k0);
          UNR for (int m = 0; m < 4; ++m) {
            f16x8 A1 = *(const f16x8*)&hall[pb + (m >> 1) * SLOT_ + lswz((m & 1) * 16 + l15, k0)];
            tR[m]  = MFMA16(A1, BhR, tR[m]);
            tZ[m]  = MFMA16(A1, BhZ, tZ[m]);
            tNh[m] = MFMA16(A1, BhN, tNh[m]);
          }
        }
      }
      UNR for (int m = 0; m < 4; ++m) {
        UNR for (int e = 0; e < 4; ++e) {
          const int lrow = (m & 1) * 16 + lg4 + e;
          float r  = sigm(tR[m][e] + b1r_c);
          float z  = sigm(tZ[m][e] + b1z_c);
          float n  = tanh_fast(tNi[m][e] + b1ni_c + r * (tNh[m][e] + b1nh_c));
          float ho = (float)hall[pb + (m >> 1) * SLOT_ + lswz(lrow, col)];
          hall[pa + (m >> 1) * SLOT_ + lswz(lrow, col)] = (f16)(n + z * (ho - n));
        }
      }
    }
    __syncthreads();

    // ================= amplitude head (reads pa = h1_new) =================
    if (t >= 0) {
      float d0 = 0.f, d1 = 0.f;
      #pragma unroll
      for (int j = 0; j < 2; ++j) {
        const int k0 = t16 * 16 + j * 8;
        f16x8 hv = *(const f16x8*)&hall[pa + (hrow >> 5) * SLOT_ + lswz(hrow & 31, k0)];
        f32x4 w0a = *(const f32x4*)&wampL[k0];
        f32x4 w0b = *(const f32x4*)&wampL[k0 + 4];
        f32x4 w1a = *(const f32x4*)&wampL[256 + k0];
        f32x4 w1b = *(const f32x4*)&wampL[256 + k0 + 4];
        #pragma unroll
        for (int i = 0; i < 4; ++i) {
          float hfa = (float)hv[i], hfb = (float)hv[4 + i];
          d0 = fmaf(hfa, w0a[i], d0); d0 = fmaf(hfb, w0b[i], d0);
          d1 = fmaf(hfa, w1a[i], d1); d1 = fmaf(hfb, w1b[i], d1);
        }
      }
      d0 += __shfl_xor(d0, 1); d0 += __shfl_xor(d0, 2);
      d0 += __shfl_xor(d0, 4); d0 += __shfl_xor(d0, 8);
      d1 += __shfl_xor(d1, 1); d1 += __shfl_xor(d1, 2);
      d1 += __shfl_xor(d1, 4); d1 += __shfl_xor(d1, 8);
      const unsigned hm = hhi ? hi32 : lo32;
      const int bit = (hm >> hsh) & 1;
      float diff = (d0 + ba0) - (d1 + ba1);
      if (bit) diff = -diff;
      prob *= __builtin_amdgcn_rcpf(1.0f + __builtin_amdgcn_exp2f(diff * -1.442695040888963f));
    }

    // rotate pairs: h0_cur := pc, h1_cur := pa, free := pb
    int tmp = pa; pa = pc; pc = pb; pb = tmp;
  }

  if (t16 == 0) out[rowbase + hrow] = sqrtf(prob);
}

extern "C" void kernel_launch(void* const* d_in, const int* in_sizes, int n_in,
                              void* d_out, int out_size, void* d_ws, size_t ws_size,
                              hipStream_t stream) {
  const int*   x     = (const int*)d_in[0];
  const float* w_ih0 = (const float*)d_in[1];
  const float* w_hh0 = (const float*)d_in[2];
  const float* b_ih0 = (const float*)d_in[3];
  const float* b_hh0 = (const float*)d_in[4];
  const float* w_ih1 = (const float*)d_in[5];
  const float* w_hh1 = (const float*)d_in[6];
  const float* b_ih1 = (const float*)d_in[7];
  const float* b_hh1 = (const float*)d_in[8];
  const float* w_amp = (const float*)d_in[9];
  const float* b_amp = (const float*)d_in[10];
  (void)in_sizes; (void)n_in; (void)out_size; (void)ws_size;

  f16* W16 = (f16*)d_ws;   // 3*768*256*2 = 1.18 MB of workspace
  hipLaunchKernelGGL(wcvt, dim3(768), dim3(256), 0, stream, w_hh0, w_ih1, w_hh1, W16);
  hipLaunchKernelGGL(rnnwf, dim3(32768 / TB_), dim3(NT_), 0, stream,
                     x, w_ih0, b_ih0, b_hh0, b_ih1, b_hh1, w_amp, b_amp, W16,
                     (float*)d_out);
}

// Round 19
// 5004.637 us; speedup vs baseline: 1.4171x; 1.1097x over previous
//
#include <hip/hip_runtime.h>

typedef _Float16 f16;
typedef _Float16 f16x8 __attribute__((ext_vector_type(8)));
typedef float f32x4 __attribute__((ext_vector_type(4)));

#define H_    256
#define TB_   64      // batch rows per workgroup
#define NT_   1024    // 16 waves, 4 per SIMD
#define SORB_ 64
#define SLOT_ 8192    // 32 rows * 256 cols f16 = 16 KB; a pair (64 rows) = 2 slots

#define MFMA16(a, b, c) __builtin_amdgcn_mfma_f32_16x16x32_f16((a), (b), (c), 0, 0, 0)
#define UNR _Pragma("unroll")

// fast activations: native v_exp_f32 (computes 2^x) + v_rcp_f32; rel err ~1e-7
__device__ __forceinline__ float sigm(float v) {
  return __builtin_amdgcn_rcpf(1.0f + __builtin_amdgcn_exp2f(v * -1.442695040888963f));
}
__device__ __forceinline__ float tanh_fast(float v) {
  float a = fabsf(v);
  float e = __builtin_amdgcn_exp2f(a * -2.885390081777927f);
  float t = (1.0f - e) * __builtin_amdgcn_rcpf(1.0f + e);
  return copysignf(t, v);
}
// XOR-swizzle within a 32-row slot (f16 units, 16B granule)
__device__ __forceinline__ int lswz(int lrow, int col) {
  return lrow * H_ + (col ^ ((lrow & 7) << 3));
}

// fp32 -> f16 weight conversion: [whh0 | wih1 | whh1], each [768][256] row-major
__global__ void wcvt(const float* __restrict__ a, const float* __restrict__ b,
                     const float* __restrict__ c, f16* __restrict__ o) {
  int i = blockIdx.x * 256 + threadIdx.x;
  const int n = 768 * 256;
  if (i < n) {
    o[i]         = (f16)a[i];
    o[n + i]     = (f16)b[i];
    o[2 * n + i] = (f16)c[i];
  }
}

__global__ __launch_bounds__(NT_, 4) void rnnwf(
    const int* __restrict__ x,
    const float* __restrict__ w_ih0, const float* __restrict__ b_ih0,
    const float* __restrict__ b_hh0, const float* __restrict__ b_ih1,
    const float* __restrict__ b_hh1, const float* __restrict__ w_amp,
    const float* __restrict__ b_amp, const f16* __restrict__ W16,
    float* __restrict__ out)
{
  __shared__ __align__(16) f16 hall[6 * SLOT_];  // 96 KB: 3 pairs of 64 rows
  __shared__ float wampL[512];
  __shared__ unsigned short bitsL[TB_ * 4];
  __shared__ unsigned long long bitsT[SORB_];    // bit r of bitsT[t] = x[row r][t]

  const int tid  = threadIdx.x;
  const int wave = tid >> 6;                  // 0..15
  const int lane = tid & 63;
  const int l15  = lane & 15;
  const int lg   = lane >> 4;                 // 0..3
  const int lg4  = lg << 2;
  const int col  = wave * 16 + l15;           // fixed hidden column per thread
  const int rowbase = blockIdx.x * TB_;

  // ---- one-time setup ----
  for (int j = tid; j < 512; j += NT_) wampL[j] = w_amp[j];
  if (tid < 256) {
    int row = tid >> 2, q = tid & 3;
    const int* xp = x + (size_t)(rowbase + row) * SORB_ + q * 16;
    unsigned m = 0;
    #pragma unroll
    for (int i = 0; i < 16; ++i) m |= (unsigned)(xp[i] & 1) << i;
    bitsL[row * 4 + q] = (unsigned short)m;
  }
  for (int i = tid; i < 6 * SLOT_; i += NT_) hall[i] = (f16)0.f;

  // per-thread L0 gate tables: sum0 (bit=0) and sum1 (bit=1) per gate.
  // sum1 = sum0 + delta rounded once -- bitwise-identical to the fma it replaces.
  const float baseR = b_ih0[col]       + b_hh0[col];
  const float baseZ = b_ih0[256 + col] + b_hh0[256 + col];
  const float baseN = b_ih0[512 + col];
  const float sumR0 = baseR + w_ih0[2 * col + 0];
  const float sumZ0 = baseZ + w_ih0[2 * (256 + col) + 0];
  const float sumN0 = baseN + w_ih0[2 * (512 + col) + 0];
  const float sumR1 = sumR0 + (w_ih0[2 * col + 1]         - w_ih0[2 * col + 0]);
  const float sumZ1 = sumZ0 + (w_ih0[2 * (256 + col) + 1] - w_ih0[2 * (256 + col) + 0]);
  const float sumN1 = sumN0 + (w_ih0[2 * (512 + col) + 1] - w_ih0[2 * (512 + col) + 0]);
  const float bhh0n_c = b_hh0[512 + col];
  const float b1r_c   = b_ih1[col]       + b_hh1[col];
  const float b1z_c   = b_ih1[256 + col] + b_hh1[256 + col];
  const float b1ni_c  = b_ih1[512 + col];
  const float b1nh_c  = b_hh1[512 + col];
  const float ba0 = b_amp[0], ba1 = b_amp[1];
  __syncthreads();

  // transpose bit matrix: bitsT[t] holds bit-per-row for step t (broadcast read later)
  if (tid < SORB_) {
    unsigned long long mk = 0ull;
    const int q = tid >> 4, sh = tid & 15;
    #pragma unroll 4
    for (int r = 0; r < TB_; ++r)
      mk |= (unsigned long long)((bitsL[r * 4 + q] >> sh) & 1) << r;
    bitsT[tid] = mk;
  }
  __syncthreads();

  float prob = 1.0f;
  const f16* Wih1 = W16 + 768 * 256;
  const f16* Whh1 = W16 + 2 * 768 * 256;
  const f16* p0base = W16  + col * 256;
  const f16* pibase = Wih1 + col * 256;
  const f16* phbase = Whh1 + col * 256;

  // head constants
  const int hrow = tid >> 4;            // 0..63
  const int t16  = tid & 15;
  const int hsh  = hrow & 31;
  const bool hhi = hrow >= 32;

  int pa = 0, pb = 2 * SLOT_, pc = 4 * SLOT_;   // h0_cur, h1_cur, free

  for (int t = -1; t < SORB_; ++t) {
    unsigned lo32 = 0u, hi32 = 0u;
    if (t >= 0) {
      unsigned long long mk = bitsT[t];        // uniform address -> broadcast
      lo32 = (unsigned)mk; hi32 = (unsigned)(mk >> 32);
    }

    // ================= layer 0: read pa -> write pc =================
    {
      f32x4 aR[4], aZ[4], aN[4];
      UNR for (int m = 0; m < 4; ++m) { aR[m] = (f32x4){0,0,0,0}; aZ[m] = aR[m]; aN[m] = aR[m]; }
      #pragma unroll 2
      for (int kt = 0; kt < 8; ++kt) {
        const int k0 = kt * 32 + lg * 8;
        f16x8 Br = *(const f16x8*)(p0base + k0);
        f16x8 Bz = *(const f16x8*)(p0base + 65536 + k0);
        f16x8 Bn = *(const f16x8*)(p0base + 131072 + k0);
        UNR for (int m = 0; m < 4; ++m) {
          f16x8 A = *(const f16x8*)&hall[pa + (m >> 1) * SLOT_ + lswz((m & 1) * 16 + l15, k0)];
          aR[m] = MFMA16(A, Br, aR[m]);
          aZ[m] = MFMA16(A, Bz, aZ[m]);
          aN[m] = MFMA16(A, Bn, aN[m]);
        }
      }
      if (t >= 0) {
        UNR for (int m = 0; m < 4; ++m) {
          const unsigned hsel = (m < 2) ? lo32 : hi32;
          UNR for (int e = 0; e < 4; ++e) {
            const int lrow = (m & 1) * 16 + lg4 + e;
            const bool bset = (hsel >> ((m & 1) * 16 + lg4 + e)) & 1u;
            float r  = sigm(aR[m][e] + (bset ? sumR1 : sumR0));
            float z  = sigm(aZ[m][e] + (bset ? sumZ1 : sumZ0));
            float n  = tanh_fast((bset ? sumN1 : sumN0) + r * (aN[m][e] + bhh0n_c));
            float ho = (float)hall[pa + (m >> 1) * SLOT_ + lswz(lrow, col)];
            hall[pc + (m >> 1) * SLOT_ + lswz(lrow, col)] = (f16)(n + z * (ho - n));
          }
        }
      } else {
        UNR for (int m = 0; m < 4; ++m) {
          UNR for (int e = 0; e < 4; ++e) {
            const int lrow = (m & 1) * 16 + lg4 + e;
            float r  = sigm(aR[m][e] + baseR);
            float z  = sigm(aZ[m][e] + baseZ);
            float n  = tanh_fast(baseN + r * (aN[m][e] + bhh0n_c));
            float ho = (float)hall[pa + (m >> 1) * SLOT_ + lswz(lrow, col)];
            hall[pc + (m >> 1) * SLOT_ + lswz(lrow, col)] = (f16)(n + z * (ho - n));
          }
        }
      }
    }
    __syncthreads();

    // ===== layer 1: read pc (h0') + pb (h1) -> write pa =====
    // ONE kt loop (unroll 1 -- R18 showed unroll 2 spills), four gate accumulator
    // sets (64 accs -> AGPR file), B loaded once per kt, A0/A1 once per kt,
    // element-wise epilogue keeps arch live-set < 64.
    {
      f32x4 tR[4], tZ[4], tNi[4], tNh[4];
      UNR for (int m = 0; m < 4; ++m) {
        tR[m] = (f32x4){0,0,0,0}; tZ[m] = tR[m]; tNi[m] = tR[m]; tNh[m] = tR[m];
      }
      #pragma unroll 1
      for (int kt = 0; kt < 8; ++kt) {
        const int k0 = kt * 32 + lg * 8;
        {  // ih source: 3 B streams live, A0 loaded per-m
          f16x8 BiR = *(const f16x8*)(pibase + k0);
          f16x8 BiZ = *(const f16x8*)(pibase + 65536 + k0);
          f16x8 BiN = *(const f16x8*)(pibase + 131072 + k0);
          UNR for (int m = 0; m < 4; ++m) {
            f16x8 A0 = *(const f16x8*)&hall[pc + (m >> 1) * SLOT_ + lswz((m & 1) * 16 + l15, k0)];
            tR[m]  = MFMA16(A0, BiR, tR[m]);
            tZ[m]  = MFMA16(A0, BiZ, tZ[m]);
            tNi[m] = MFMA16(A0, BiN, tNi[m]);
          }
        }
        {  // hh source
          f16x8 BhR = *(const f16x8*)(phbase + k0);
          f16x8 BhZ = *(const f16x8*)(phbase + 65536 + k0);
          f16x8 BhN = *(const f16x8*)(phbase + 131072 + k0);
          UNR for (int m = 0; m < 4; ++m) {
            f16x8 A1 = *(const f16x8*)&hall[pb + (m >> 1) * SLOT_ + lswz((m & 1) * 16 + l15, k0)];
            tR[m]  = MFMA16(A1, BhR, tR[m]);
            tZ[m]  = MFMA16(A1, BhZ, tZ[m]);
            tNh[m] = MFMA16(A1, BhN, tNh[m]);
          }
        }
      }
      UNR for (int m = 0; m < 4; ++m) {
        UNR for (int e = 0; e < 4; ++e) {
          const int lrow = (m & 1) * 16 + lg4 + e;
          float r  = sigm(tR[m][e] + b1r_c);
          float z  = sigm(tZ[m][e] + b1z_c);
          float n  = tanh_fast(tNi[m][e] + b1ni_c + r * (tNh[m][e] + b1nh_c));
          float ho = (float)hall[pb + (m >> 1) * SLOT_ + lswz(lrow, col)];
          hall[pa + (m >> 1) * SLOT_ + lswz(lrow, col)] = (f16)(n + z * (ho - n));
        }
      }
    }
    __syncthreads();

    // ================= amplitude head (reads pa = h1_new) =================
    if (t >= 0) {
      float d0 = 0.f, d1 = 0.f;
      #pragma unroll
      for (int j = 0; j < 2; ++j) {
        const int k0 = t16 * 16 + j * 8;
        f16x8 hv = *(const f16x8*)&hall[pa + (hrow >> 5) * SLOT_ + lswz(hrow & 31, k0)];
        f32x4 w0a = *(const f32x4*)&wampL[k0];
        f32x4 w0b = *(const f32x4*)&wampL[k0 + 4];
        f32x4 w1a = *(const f32x4*)&wampL[256 + k0];
        f32x4 w1b = *(const f32x4*)&wampL[256 + k0 + 4];
        #pragma unroll
        for (int i = 0; i < 4; ++i) {
          float hfa = (float)hv[i], hfb = (float)hv[4 + i];
          d0 = fmaf(hfa, w0a[i], d0); d0 = fmaf(hfb, w0b[i], d0);
          d1 = fmaf(hfa, w1a[i], d1); d1 = fmaf(hfb, w1b[i], d1);
        }
      }
      d0 += __shfl_xor(d0, 1); d0 += __shfl_xor(d0, 2);
      d0 += __shfl_xor(d0, 4); d0 += __shfl_xor(d0, 8);
      d1 += __shfl_xor(d1, 1); d1 += __shfl_xor(d1, 2);
      d1 += __shfl_xor(d1, 4); d1 += __shfl_xor(d1, 8);
      const unsigned hm = hhi ? hi32 : lo32;
      const int bit = (hm >> hsh) & 1;
      float diff = (d0 + ba0) - (d1 + ba1);
      if (bit) diff = -diff;
      prob *= __builtin_amdgcn_rcpf(1.0f + __builtin_amdgcn_exp2f(diff * -1.442695040888963f));
    }

    // rotate pairs: h0_cur := pc, h1_cur := pa, free := pb
    int tmp = pa; pa = pc; pc = pb; pb = tmp;
  }

  if (t16 == 0) out[rowbase + hrow] = sqrtf(prob);
}

extern "C" void kernel_launch(void* const* d_in, const int* in_sizes, int n_in,
                              void* d_out, int out_size, void* d_ws, size_t ws_size,
                              hipStream_t stream) {
  const int*   x     = (const int*)d_in[0];
  const float* w_ih0 = (const float*)d_in[1];
  const float* w_hh0 = (const float*)d_in[2];
  const float* b_ih0 = (const float*)d_in[3];
  const float* b_hh0 = (const float*)d_in[4];
  const float* w_ih1 = (const float*)d_in[5];
  const float* w_hh1 = (const float*)d_in[6];
  const float* b_ih1 = (const float*)d_in[7];
  const float* b_hh1 = (const float*)d_in[8];
  const float* w_amp = (const float*)d_in[9];
  const float* b_amp = (const float*)d_in[10];
  (void)in_sizes; (void)n_in; (void)out_size; (void)ws_size;

  f16* W16 = (f16*)d_ws;   // 3*768*256*2 = 1.18 MB of workspace
  hipLaunchKernelGGL(wcvt, dim3(768), dim3(256), 0, stream, w_hh0, w_ih1, w_hh1, W16);
  hipLaunchKernelGGL(rnnwf, dim3(32768 / TB_), dim3(NT_), 0, stream,
                     x, w_ih0, b_ih0, b_hh0, b_ih1, b_hh1, w_amp, b_amp, W16,
                     (float*)d_out);
}